// Round 2
// baseline (120.231 us; speedup 1.0000x reference)
//
#include <hip/hip_runtime.h>
#include <math.h>

// Problem constants
#define B_   4
#define DM   64   // d_model
#define DS   16   // d_state
#define HH_  32
#define WW_  32
#define HW_  1024 // 32*32
#define NV   9    // (2*1+1)^2 shifts

// d_out layout: y_out (B,9,64,32,32) = 2359296 floats, then s_next (B,9,64,16,32,32)
#define Y_SIZE   2359296
// ws layout (floats): delta[B][64][1024], B_val[B][16][1024], C_val[B][16][1024]
#define WS_DELTA 0
#define WS_BV    (B_*DM*HW_)            // 262144
#define WS_CV    (WS_BV + B_*DS*HW_)    // 327680

// ---------------------------------------------------------------------------
// Kernel 1: the three circular 3x3 convolutions (unchanged from R1 — passed,
// small share of runtime).
// ---------------------------------------------------------------------------
__global__ __launch_bounds__(1024) void conv_kernel(
    const float* __restrict__ u,
    const float* __restrict__ Wd,
    const float* __restrict__ bd,
    const float* __restrict__ Wb,
    const float* __restrict__ Wc,
    const float* __restrict__ dtp,
    float* __restrict__ ws)
{
    __shared__ float su[HW_];
    __shared__ float sw[DM * 9 * 4];   // [ci][tap][j]  (j = 4 output channels)

    const int bid = blockIdx.x;
    const int b   = bid / 24;
    const int g   = bid % 24;
    const int co0 = g * 4;

    const float* Wsrc;
    int cbase, mode;
    if (co0 < 64)      { Wsrc = Wd; cbase = co0;      mode = 0; }
    else if (co0 < 80) { Wsrc = Wb; cbase = co0 - 64; mode = 1; }
    else               { Wsrc = Wc; cbase = co0 - 80; mode = 2; }

    const int tid = threadIdx.x;

    for (int i = tid; i < DM * 9 * 4; i += 1024) {
        const int j  = i & 3;
        const int ct = i >> 2;          // ci*9 + tap
        sw[i] = Wsrc[(cbase + j) * 576 + ct];
    }

    const int h = tid >> 5;
    const int w = tid & 31;

    float acc0 = 0.f, acc1 = 0.f, acc2 = 0.f, acc3 = 0.f;
    const float* ub = u + (size_t)b * DM * HW_;

    for (int ci = 0; ci < DM; ++ci) {
        __syncthreads();
        su[tid] = ub[ci * HW_ + tid];
        __syncthreads();
        #pragma unroll
        for (int kh = 0; kh < 3; ++kh) {
            const int hh = (h + kh + 31) & 31;
            #pragma unroll
            for (int kw = 0; kw < 3; ++kw) {
                const int ww = (w + kw + 31) & 31;
                const float v = su[(hh << 5) | ww];
                const float4 wv = *(const float4*)&sw[(ci * 9 + kh * 3 + kw) * 4];
                acc0 = fmaf(v, wv.x, acc0);
                acc1 = fmaf(v, wv.y, acc1);
                acc2 = fmaf(v, wv.z, acc2);
                acc3 = fmaf(v, wv.w, acc3);
            }
        }
    }

    float acc[4] = {acc0, acc1, acc2, acc3};
    if (mode == 0) {
        const float dt = dtp[0];
        #pragma unroll
        for (int j = 0; j < 4; ++j) {
            const float x  = acc[j] + bd[cbase + j] + dt;
            const float sp = fmaxf(x, 0.f) + log1pf(expf(-fabsf(x)));
            ws[WS_DELTA + ((size_t)b * DM + cbase + j) * HW_ + tid] = sp;
        }
    } else if (mode == 1) {
        #pragma unroll
        for (int j = 0; j < 4; ++j)
            ws[WS_BV + ((size_t)b * DS + cbase + j) * HW_ + tid] = acc[j];
    } else {
        #pragma unroll
        for (int j = 0; j < 4; ++j)
            ws[WS_CV + ((size_t)b * DS + cbase + j) * HW_ + tid] = acc[j];
    }
}

// ---------------------------------------------------------------------------
// Kernel 2 (v2): state update + output, parallel over v as well.
// One thread per (b,v,c,h,w) = 2,359,296 threads = 36,864 waves.
// Per thread: tiny 16-iteration n-loop, no register arrays (~20 VGPR).
// A[n] and 1/A[n] hoisted to LDS (c is uniform per 256-thread block).
// ---------------------------------------------------------------------------
__global__ __launch_bounds__(256) void scan_kernel(
    const float* __restrict__ u,
    const float* __restrict__ s_prev,
    const float* __restrict__ logA,
    const float* __restrict__ Dv,
    const float* __restrict__ ws,
    float* __restrict__ out)
{
    const int t  = blockIdx.x * 256 + threadIdx.x;   // 0 .. B*NV*DM*HW-1
    const int hw = t & 1023;
    const int w  = t & 31;
    const int h  = (hw >> 5);
    const int c  = (t >> 10) & 63;   // uniform within block
    const int bv = t >> 16;          // b*9 + v, uniform within block
    const int v  = bv % 9;
    const int b  = bv / 9;

    __shared__ float sA[DS], sInvA[DS];
    if (threadIdx.x < DS) {
        const float A = -expf(logA[(c << 4) + threadIdx.x]);
        sA[threadIdx.x]    = A;
        sInvA[threadIdx.x] = 1.0f / A;
    }
    __syncthreads();

    const int sx = v / 3 - 1;                 // SHIFTS order: x outer, y inner
    const int sy = v % 3 - 1;
    const int hs  = (h + sy) & 31;
    const int ws2 = (w + sx) & 31;
    const int shw = (hs << 5) | ws2;

    const int bc = (b << 6) | c;              // b*64 + c
    const float u_val = u[(bc << 10) | hw];
    const float delta = ws[WS_DELTA + ((bc << 10) | hw)];

    const size_t base = ((size_t)(t >> 10)) << 14;   // ((b*9+v)*64+c) * 16 * 1024
    const float* __restrict__ sp = s_prev + base;
    float* __restrict__ so = out + Y_SIZE + base;

    const int bvw = ((b << 4) << 10) + hw;    // base index into BV/CV slabs

    float acc = 0.f;
    #pragma unroll
    for (int n = 0; n < DS; ++n) {
        const float A    = sA[n];
        const float e    = expf(delta * A);            // A_bar
        const float Bb   = (e - 1.0f) * sInvA[n] * ws[WS_BV + bvw + (n << 10)];
        const float bu   = Bb * u_val;
        const float s    = fmaf(e, sp[(n << 10) + shw], bu);
        so[(n << 10) + hw] = s;
        acc = fmaf(s, ws[WS_CV + bvw + (n << 10)], acc);
    }
    out[t] = acc + u_val * Dv[c];
}

extern "C" void kernel_launch(void* const* d_in, const int* in_sizes, int n_in,
                              void* d_out, int out_size, void* d_ws, size_t ws_size,
                              hipStream_t stream) {
    const float* u      = (const float*)d_in[0];
    const float* s_prev = (const float*)d_in[1];
    const float* Wd     = (const float*)d_in[2];
    const float* bd     = (const float*)d_in[3];
    const float* Wb     = (const float*)d_in[4];
    const float* Wc     = (const float*)d_in[5];
    const float* logA   = (const float*)d_in[6];
    const float* Dv     = (const float*)d_in[7];
    const float* dtp    = (const float*)d_in[8];
    float* out = (float*)d_out;
    float* ws  = (float*)d_ws;

    conv_kernel<<<B_ * 24, 1024, 0, stream>>>(u, Wd, bd, Wb, Wc, dtp, ws);
    scan_kernel<<<(B_ * NV * DM * HW_) / 256, 256, 0, stream>>>(u, s_prev, logA, Dv, ws, out);
}

// Round 4
// 101.531 us; speedup vs baseline: 1.1842x; 1.1842x over previous
//
#include <hip/hip_runtime.h>
#include <math.h>

// Problem constants
#define B_   4
#define DM   64   // d_model
#define DS   16   // d_state
#define HW_  1024 // 32*32
#define NV   9    // (2*1+1)^2 shifts

typedef float f32x4 __attribute__((ext_vector_type(4)));

// d_out layout: y_out (B,9,64,32,32) = 2359296 floats, then s_next (B,9,64,16,32,32)
#define Y_SIZE   2359296
// ws layout (floats): delta[B][64][1024], B_val[B][16][1024], C_val[B][16][1024]
#define WS_DELTA 0
#define WS_BV    (B_*DM*HW_)            // 262144
#define WS_CV    (WS_BV + B_*DS*HW_)    // 327680

// ---------------------------------------------------------------------------
// Kernel 1 (v2): three circular 3x3 convs, split spatially 4x for parallelism.
// Grid: B * 24 * 4 = 384 blocks, 256 threads (8 rows x 32 cols each).
// ---------------------------------------------------------------------------
__global__ __launch_bounds__(256) void conv_kernel(
    const float* __restrict__ u,
    const float* __restrict__ Wd,
    const float* __restrict__ bd,
    const float* __restrict__ Wb,
    const float* __restrict__ Wc,
    const float* __restrict__ dtp,
    float* __restrict__ ws)
{
    __shared__ float su[10 * 32];      // rows h0-1 .. h0+8 (wrapped)
    __shared__ float sw[DM * 9 * 4];   // [ci][tap][j]  (j = 4 output channels)

    const int bid = blockIdx.x;
    const int b   = bid / 96;
    const int r   = bid % 96;
    const int g   = r >> 2;            // 0..23 channel-group
    const int h0  = (r & 3) * 8;       // row-quarter base
    const int co0 = g * 4;

    const float* Wsrc;
    int cbase, mode;
    if (co0 < 64)      { Wsrc = Wd; cbase = co0;      mode = 0; }
    else if (co0 < 80) { Wsrc = Wb; cbase = co0 - 64; mode = 1; }
    else               { Wsrc = Wc; cbase = co0 - 80; mode = 2; }

    const int tid = threadIdx.x;

    // stage weights: sw[(ci*9+tap)*4 + j] = Wsrc[(cbase+j)*576 + ci*9+tap]
    for (int i = tid; i < DM * 9 * 4; i += 256) {
        const int j  = i & 3;
        const int ct = i >> 2;          // ci*9 + tap
        sw[i] = Wsrc[(cbase + j) * 576 + ct];
    }

    const int hl = tid >> 5;            // 0..7 local row
    const int w  = tid & 31;
    const int pix = ((h0 + hl) << 5) | w;

    float acc0 = 0.f, acc1 = 0.f, acc2 = 0.f, acc3 = 0.f;
    const float* ub = u + (size_t)b * DM * HW_;

    for (int ci = 0; ci < DM; ++ci) {
        __syncthreads();                 // covers weight staging on first iter
        // stage 10 rows (h0-1 .. h0+8, wrapped)
        for (int i = tid; i < 320; i += 256) {
            const int rr = i >> 5;
            su[i] = ub[ci * HW_ + ((((h0 - 1 + rr) & 31) << 5) | (i & 31))];
        }
        __syncthreads();
        #pragma unroll
        for (int kh = 0; kh < 3; ++kh) {
            const int rs = hl + kh;      // su row: (h0-1+rs) == h+kh-1
            #pragma unroll
            for (int kw = 0; kw < 3; ++kw) {
                const int ww = (w + kw + 31) & 31;
                const float v = su[(rs << 5) | ww];
                const float4 wv = *(const float4*)&sw[(ci * 9 + kh * 3 + kw) * 4];
                acc0 = fmaf(v, wv.x, acc0);
                acc1 = fmaf(v, wv.y, acc1);
                acc2 = fmaf(v, wv.z, acc2);
                acc3 = fmaf(v, wv.w, acc3);
            }
        }
    }

    float acc[4] = {acc0, acc1, acc2, acc3};
    if (mode == 0) {
        const float dt = dtp[0];
        #pragma unroll
        for (int j = 0; j < 4; ++j) {
            const float x  = acc[j] + bd[cbase + j] + dt;
            const float sp = fmaxf(x, 0.f) + log1pf(expf(-fabsf(x)));
            ws[WS_DELTA + ((size_t)b * DM + cbase + j) * HW_ + pix] = sp;
        }
    } else if (mode == 1) {
        #pragma unroll
        for (int j = 0; j < 4; ++j)
            ws[WS_BV + ((size_t)b * DS + cbase + j) * HW_ + pix] = acc[j];
    } else {
        #pragma unroll
        for (int j = 0; j < 4; ++j)
            ws[WS_CV + ((size_t)b * DS + cbase + j) * HW_ + pix] = acc[j];
    }
}

// ---------------------------------------------------------------------------
// Kernel 2 (v3): float4-vectorized state update. One block per (b,v,c) plane
// slab: 256 threads x 4 pixels = 1024 pixels. w-shift via aligned float4 load
// + one __shfl for the edge element (8 lanes per 32-px row).
// n-loop in chunks of 4: 12 float4 loads batched, then compute + 4 NT stores.
// ---------------------------------------------------------------------------
__global__ __launch_bounds__(256) void scan_kernel(
    const float* __restrict__ u,
    const float* __restrict__ s_prev,
    const float* __restrict__ logA,
    const float* __restrict__ Dv,
    const float* __restrict__ ws,
    float* __restrict__ out)
{
    const int bid = blockIdx.x;      // (b*9+v)*64 + c
    const int c   = bid & 63;
    const int bv  = bid >> 6;
    const int v   = bv % 9;
    const int b   = bv / 9;

    __shared__ float sA[DS], sInvA[DS];
    if (threadIdx.x < DS) {
        const float A = -expf(logA[(c << 4) + (int)threadIdx.x]);
        sA[threadIdx.x]    = A;
        sInvA[threadIdx.x] = 1.0f / A;
    }
    __syncthreads();

    const int q    = threadIdx.x;
    const int hw4  = q << 2;         // first of 4 pixels
    const int h    = q >> 3;
    const int lane = q & 63;

    const int sx = v / 3 - 1;        // SHIFTS order: x outer, y inner
    const int sy = v % 3 - 1;
    const int hs = (h + sy) & 31;
    const int rowbase = (hs << 5) | ((q & 7) << 2);   // aligned col group

    const int srcp = (lane & ~7) | ((lane + 1) & 7);  // next lane in row
    const int srcm = (lane & ~7) | ((lane + 7) & 7);  // prev lane in row

    const int bc = (b << 6) | c;
    const float4 u4 = *(const float4*)&u[(bc << 10) | hw4];
    const float4 d4 = *(const float4*)&ws[WS_DELTA + ((bc << 10) | hw4)];

    const float* __restrict__ sp  = s_prev + ((size_t)bid << 14);
    float* __restrict__ so        = out + Y_SIZE + ((size_t)bid << 14);
    const float* __restrict__ bvp = ws + WS_BV + ((b << 14) | hw4);
    const float* __restrict__ cvp = ws + WS_CV + ((b << 14) | hw4);

    float4 acc = make_float4(0.f, 0.f, 0.f, 0.f);

    #pragma unroll
    for (int chunk = 0; chunk < 4; ++chunk) {
        float4 spv[4], bvv[4], cvv[4];
        #pragma unroll
        for (int i = 0; i < 4; ++i) {
            const int n = chunk * 4 + i;
            spv[i] = *(const float4*)&sp[(n << 10) + rowbase];
            bvv[i] = *(const float4*)&bvp[n << 10];
            cvv[i] = *(const float4*)&cvp[n << 10];
        }
        #pragma unroll
        for (int i = 0; i < 4; ++i) {
            const int n = chunk * 4 + i;
            // rotate-by-sx along w
            float4 sh;
            if (sx > 0) {
                const float edge = __shfl(spv[i].x, srcp);
                sh = make_float4(spv[i].y, spv[i].z, spv[i].w, edge);
            } else if (sx < 0) {
                const float edge = __shfl(spv[i].w, srcm);
                sh = make_float4(edge, spv[i].x, spv[i].y, spv[i].z);
            } else {
                sh = spv[i];
            }
            const float A  = sA[n];
            const float iA = sInvA[n];
            float4 e;
            f32x4 s;
            e.x = expf(d4.x * A);
            e.y = expf(d4.y * A);
            e.z = expf(d4.z * A);
            e.w = expf(d4.w * A);
            s.x = fmaf(e.x, sh.x, (e.x - 1.f) * iA * bvv[i].x * u4.x);
            s.y = fmaf(e.y, sh.y, (e.y - 1.f) * iA * bvv[i].y * u4.y);
            s.z = fmaf(e.z, sh.z, (e.z - 1.f) * iA * bvv[i].z * u4.z);
            s.w = fmaf(e.w, sh.w, (e.w - 1.f) * iA * bvv[i].w * u4.w);
            __builtin_nontemporal_store(s, (f32x4*)&so[(n << 10) + hw4]);
            acc.x = fmaf(s.x, cvv[i].x, acc.x);
            acc.y = fmaf(s.y, cvv[i].y, acc.y);
            acc.z = fmaf(s.z, cvv[i].z, acc.z);
            acc.w = fmaf(s.w, cvv[i].w, acc.w);
        }
    }

    const float Dc = Dv[c];
    f32x4 y;
    y.x = acc.x + u4.x * Dc;
    y.y = acc.y + u4.y * Dc;
    y.z = acc.z + u4.z * Dc;
    y.w = acc.w + u4.w * Dc;
    __builtin_nontemporal_store(y, (f32x4*)&out[(bid << 10) | hw4]);
}

extern "C" void kernel_launch(void* const* d_in, const int* in_sizes, int n_in,
                              void* d_out, int out_size, void* d_ws, size_t ws_size,
                              hipStream_t stream) {
    const float* u      = (const float*)d_in[0];
    const float* s_prev = (const float*)d_in[1];
    const float* Wd     = (const float*)d_in[2];
    const float* bd     = (const float*)d_in[3];
    const float* Wb     = (const float*)d_in[4];
    const float* Wc     = (const float*)d_in[5];
    const float* logA   = (const float*)d_in[6];
    const float* Dv     = (const float*)d_in[7];
    const float* dtp    = (const float*)d_in[8];
    float* out = (float*)d_out;
    float* ws  = (float*)d_ws;

    conv_kernel<<<B_ * 24 * 4, 256, 0, stream>>>(u, Wd, bd, Wb, Wc, dtp, ws);
    scan_kernel<<<B_ * NV * DM, 256, 0, stream>>>(u, s_prev, logA, Dv, ws, out);
}

// Round 5
// 75.312 us; speedup vs baseline: 1.5964x; 1.3481x over previous
//
#include <hip/hip_runtime.h>
#include <math.h>

// Problem constants
#define B_   4
#define DM   64   // d_model
#define DS   16   // d_state
#define HW_  1024 // 32*32
#define NV   9    // (2*1+1)^2 shifts

typedef float f32x4 __attribute__((ext_vector_type(4)));

// d_out layout: y_out (B,9,64,32,32) = 2359296 floats, then s_next (B,9,64,16,32,32)
#define Y_SIZE   2359296
// ws layout (floats): delta[B][64][1024], B_val[B][16][1024], C_val[B][16][1024]
#define WS_DELTA 0
#define WS_BV    (B_*DM*HW_)            // 262144
#define WS_CV    (WS_BV + B_*DS*HW_)    // 327680

// ---------------------------------------------------------------------------
// Kernel 1 (v3): three circular 3x3 convs.
// 8 output channels per thread (72 FMA per 11 LDS instrs), 8-ci LDS chunks
// (16 barriers/block instead of 128). Grid: B * 12 * 4 = 192 blocks, 256 thr.
// ---------------------------------------------------------------------------
__global__ __launch_bounds__(256) void conv_kernel(
    const float* __restrict__ u,
    const float* __restrict__ Wd,
    const float* __restrict__ bd,
    const float* __restrict__ Wb,
    const float* __restrict__ Wc,
    const float* __restrict__ dtp,
    float* __restrict__ ws)
{
    __shared__ float su[8 * 320];      // 8 ci x 10 rows x 32 cols
    __shared__ float sw[DM * 9 * 8];   // [ci][tap][j], j = 8 output channels

    const int bid = blockIdx.x;
    const int b   = bid / 48;
    const int r   = bid % 48;
    const int g   = r >> 2;            // 0..11 channel-group (of 8)
    const int h0  = (r & 3) * 8;       // row-quarter base
    const int co0 = g * 8;

    const float* Wsrc;
    int cbase, mode;
    if (co0 < 64)      { Wsrc = Wd; cbase = co0;      mode = 0; }
    else if (co0 < 80) { Wsrc = Wb; cbase = co0 - 64; mode = 1; }
    else               { Wsrc = Wc; cbase = co0 - 80; mode = 2; }

    const int tid = threadIdx.x;

    // stage weights: sw[(ci*9+tap)*8 + j] = Wsrc[(cbase+j)*576 + ci*9+tap]
    for (int i = tid; i < DM * 9 * 8; i += 256) {
        const int j  = i & 7;
        const int ct = i >> 3;          // ci*9 + tap
        sw[i] = Wsrc[(cbase + j) * 576 + ct];
    }

    const int hl = tid >> 5;            // 0..7 local row
    const int w  = tid & 31;
    const int pix = ((h0 + hl) << 5) | w;

    float acc[8];
    #pragma unroll
    for (int j = 0; j < 8; ++j) acc[j] = 0.f;
    const float* ub = u + (size_t)b * DM * HW_;

    for (int c0 = 0; c0 < DM; c0 += 8) {
        __syncthreads();                 // covers weight staging on first iter
        // stage 8 ci-planes x 10 rows (h0-1 .. h0+8, wrapped): 2560 floats
        #pragma unroll
        for (int k = 0; k < 10; ++k) {
            const int i   = k * 256 + tid;
            const int cl  = i / 320;
            const int pos = i - cl * 320;
            const int rr  = pos >> 5;
            su[i] = ub[(c0 + cl) * HW_ + ((((h0 - 1 + rr) & 31) << 5) | (pos & 31))];
        }
        __syncthreads();
        #pragma unroll
        for (int cl = 0; cl < 8; ++cl) {
            #pragma unroll
            for (int kh = 0; kh < 3; ++kh) {
                const int rs = hl + kh;      // su row: (h0-1+rs) == h+kh-1
                #pragma unroll
                for (int kw = 0; kw < 3; ++kw) {
                    const int ww = (w + kw + 31) & 31;
                    const float v = su[cl * 320 + ((rs << 5) | ww)];
                    const int wb = ((c0 + cl) * 9 + kh * 3 + kw) * 8;
                    const float4 w0 = *(const float4*)&sw[wb];
                    const float4 w1 = *(const float4*)&sw[wb + 4];
                    acc[0] = fmaf(v, w0.x, acc[0]);
                    acc[1] = fmaf(v, w0.y, acc[1]);
                    acc[2] = fmaf(v, w0.z, acc[2]);
                    acc[3] = fmaf(v, w0.w, acc[3]);
                    acc[4] = fmaf(v, w1.x, acc[4]);
                    acc[5] = fmaf(v, w1.y, acc[5]);
                    acc[6] = fmaf(v, w1.z, acc[6]);
                    acc[7] = fmaf(v, w1.w, acc[7]);
                }
            }
        }
    }

    if (mode == 0) {
        const float dt = dtp[0];
        #pragma unroll
        for (int j = 0; j < 8; ++j) {
            const float x  = acc[j] + bd[cbase + j] + dt;
            const float sp = fmaxf(x, 0.f) + log1pf(expf(-fabsf(x)));
            ws[WS_DELTA + ((size_t)b * DM + cbase + j) * HW_ + pix] = sp;
        }
    } else if (mode == 1) {
        #pragma unroll
        for (int j = 0; j < 8; ++j)
            ws[WS_BV + ((size_t)b * DS + cbase + j) * HW_ + pix] = acc[j];
    } else {
        #pragma unroll
        for (int j = 0; j < 8; ++j)
            ws[WS_CV + ((size_t)b * DS + cbase + j) * HW_ + pix] = acc[j];
    }
}

// ---------------------------------------------------------------------------
// Kernel 2 (v4): float4 state update with 2-deep register software pipeline:
// next chunk's 12 loads are issued BEFORE computing the current chunk, so
// ~24 outstanding float4 loads stay in flight continuously (read-latency
// concurrency is the measured bottleneck: ~2.6 TB/s sawtooth vs 3.15 copy).
// ---------------------------------------------------------------------------
__global__ __launch_bounds__(256) void scan_kernel(
    const float* __restrict__ u,
    const float* __restrict__ s_prev,
    const float* __restrict__ logA,
    const float* __restrict__ Dv,
    const float* __restrict__ ws,
    float* __restrict__ out)
{
    const int bid = blockIdx.x;      // (b*9+v)*64 + c
    const int c   = bid & 63;
    const int bv  = bid >> 6;
    const int v   = bv % 9;
    const int b   = bv / 9;

    __shared__ float sAr[DS], sIr[DS];
    if (threadIdx.x < DS) {
        const float A = -__expf(logA[(c << 4) + (int)threadIdx.x]);
        sAr[threadIdx.x] = A;
        sIr[threadIdx.x] = 1.0f / A;
    }
    __syncthreads();

    const int q    = threadIdx.x;
    const int hw4  = q << 2;         // first of 4 pixels
    const int h    = q >> 3;
    const int lane = q & 63;

    const int sx = v / 3 - 1;        // SHIFTS order: x outer, y inner
    const int sy = v % 3 - 1;
    const int hs = (h + sy) & 31;
    const int rowbase = (hs << 5) | ((q & 7) << 2);   // aligned col group

    const int srcp = (lane & ~7) | ((lane + 1) & 7);  // next lane in row
    const int srcm = (lane & ~7) | ((lane + 7) & 7);  // prev lane in row

    const int bc = (b << 6) | c;
    const float4 u4 = *(const float4*)&u[(bc << 10) | hw4];
    const float4 d4 = *(const float4*)&ws[WS_DELTA + ((bc << 10) | hw4)];

    const float* __restrict__ sp  = s_prev + ((size_t)bid << 14);
    float* __restrict__ so        = out + Y_SIZE + ((size_t)bid << 14);
    const float* __restrict__ bvp = ws + WS_BV + ((b << 14) | hw4);
    const float* __restrict__ cvp = ws + WS_CV + ((b << 14) | hw4);

    float4 acc = make_float4(0.f, 0.f, 0.f, 0.f);

#define LOADC(SS, BB, CC, N0)                                              \
    {                                                                      \
        _Pragma("unroll")                                                  \
        for (int i = 0; i < 4; ++i) {                                      \
            const int n = (N0) + i;                                        \
            SS[i] = *(const float4*)&sp[(n << 10) + rowbase];              \
            BB[i] = *(const float4*)&bvp[n << 10];                         \
            CC[i] = *(const float4*)&cvp[n << 10];                         \
        }                                                                  \
    }

#define COMPC(SS, BB, CC, N0)                                              \
    {                                                                      \
        _Pragma("unroll")                                                  \
        for (int i = 0; i < 4; ++i) {                                      \
            const int n = (N0) + i;                                        \
            float4 sh;                                                     \
            if (sx > 0) {                                                  \
                const float edge = __shfl(SS[i].x, srcp);                  \
                sh = make_float4(SS[i].y, SS[i].z, SS[i].w, edge);         \
            } else if (sx < 0) {                                           \
                const float edge = __shfl(SS[i].w, srcm);                  \
                sh = make_float4(edge, SS[i].x, SS[i].y, SS[i].z);         \
            } else {                                                       \
                sh = SS[i];                                                \
            }                                                              \
            const float A  = sAr[n];                                       \
            const float iA = sIr[n];                                       \
            float4 e;                                                      \
            f32x4 s;                                                       \
            e.x = __expf(d4.x * A);                                        \
            e.y = __expf(d4.y * A);                                        \
            e.z = __expf(d4.z * A);                                        \
            e.w = __expf(d4.w * A);                                        \
            s.x = fmaf(e.x, sh.x, (e.x - 1.f) * iA * BB[i].x * u4.x);      \
            s.y = fmaf(e.y, sh.y, (e.y - 1.f) * iA * BB[i].y * u4.y);      \
            s.z = fmaf(e.z, sh.z, (e.z - 1.f) * iA * BB[i].z * u4.z);      \
            s.w = fmaf(e.w, sh.w, (e.w - 1.f) * iA * BB[i].w * u4.w);      \
            __builtin_nontemporal_store(s, (f32x4*)&so[(n << 10) + hw4]);  \
            acc.x = fmaf(s.x, CC[i].x, acc.x);                             \
            acc.y = fmaf(s.y, CC[i].y, acc.y);                             \
            acc.z = fmaf(s.z, CC[i].z, acc.z);                             \
            acc.w = fmaf(s.w, CC[i].w, acc.w);                             \
        }                                                                  \
    }

    float4 sa[4], ba[4], ca[4], sb[4], bb4[4], cb[4];
    LOADC(sa, ba, ca, 0);
    LOADC(sb, bb4, cb, 4);
    COMPC(sa, ba, ca, 0);
    LOADC(sa, ba, ca, 8);
    COMPC(sb, bb4, cb, 4);
    LOADC(sb, bb4, cb, 12);
    COMPC(sa, ba, ca, 8);
    COMPC(sb, bb4, cb, 12);

#undef LOADC
#undef COMPC

    const float Dc = Dv[c];
    f32x4 y;
    y.x = acc.x + u4.x * Dc;
    y.y = acc.y + u4.y * Dc;
    y.z = acc.z + u4.z * Dc;
    y.w = acc.w + u4.w * Dc;
    __builtin_nontemporal_store(y, (f32x4*)&out[(bid << 10) | hw4]);
}

extern "C" void kernel_launch(void* const* d_in, const int* in_sizes, int n_in,
                              void* d_out, int out_size, void* d_ws, size_t ws_size,
                              hipStream_t stream) {
    const float* u      = (const float*)d_in[0];
    const float* s_prev = (const float*)d_in[1];
    const float* Wd     = (const float*)d_in[2];
    const float* bd     = (const float*)d_in[3];
    const float* Wb     = (const float*)d_in[4];
    const float* Wc     = (const float*)d_in[5];
    const float* logA   = (const float*)d_in[6];
    const float* Dv     = (const float*)d_in[7];
    const float* dtp    = (const float*)d_in[8];
    float* out = (float*)d_out;
    float* ws  = (float*)d_ws;

    conv_kernel<<<B_ * 12 * 4, 256, 0, stream>>>(u, Wd, bd, Wb, Wc, dtp, ws);
    scan_kernel<<<B_ * NV * DM, 256, 0, stream>>>(u, s_prev, logA, Dv, ws, out);
}

// Round 6
// 73.247 us; speedup vs baseline: 1.6414x; 1.0282x over previous
//
#include <hip/hip_runtime.h>
#include <math.h>

// Problem constants
#define B_   4
#define DM   64   // d_model
#define DS   16   // d_state
#define HW_  1024 // 32*32
#define NV   9    // (2*1+1)^2 shifts

typedef float f32x4 __attribute__((ext_vector_type(4)));

// d_out layout: y_out (B,9,64,32,32) = 2359296 floats, then s_next (B,9,64,16,32,32)
#define Y_SIZE   2359296
// ws layout (floats): delta[B][64][1024], B_val[B][16][1024], C_val[B][16][1024]
#define WS_DELTA 0
#define WS_BV    (B_*DM*HW_)            // 262144
#define WS_CV    (WS_BV + B_*DS*HW_)    // 327680

// ---------------------------------------------------------------------------
// Kernel 1 (v3): three circular 3x3 convs. Unchanged from R5 (passed, ~8 us).
// ---------------------------------------------------------------------------
__global__ __launch_bounds__(256) void conv_kernel(
    const float* __restrict__ u,
    const float* __restrict__ Wd,
    const float* __restrict__ bd,
    const float* __restrict__ Wb,
    const float* __restrict__ Wc,
    const float* __restrict__ dtp,
    float* __restrict__ ws)
{
    __shared__ float su[8 * 320];      // 8 ci x 10 rows x 32 cols
    __shared__ float sw[DM * 9 * 8];   // [ci][tap][j], j = 8 output channels

    const int bid = blockIdx.x;
    const int b   = bid / 48;
    const int r   = bid % 48;
    const int g   = r >> 2;            // 0..11 channel-group (of 8)
    const int h0  = (r & 3) * 8;       // row-quarter base
    const int co0 = g * 8;

    const float* Wsrc;
    int cbase, mode;
    if (co0 < 64)      { Wsrc = Wd; cbase = co0;      mode = 0; }
    else if (co0 < 80) { Wsrc = Wb; cbase = co0 - 64; mode = 1; }
    else               { Wsrc = Wc; cbase = co0 - 80; mode = 2; }

    const int tid = threadIdx.x;

    for (int i = tid; i < DM * 9 * 8; i += 256) {
        const int j  = i & 7;
        const int ct = i >> 3;          // ci*9 + tap
        sw[i] = Wsrc[(cbase + j) * 576 + ct];
    }

    const int hl = tid >> 5;            // 0..7 local row
    const int w  = tid & 31;
    const int pix = ((h0 + hl) << 5) | w;

    float acc[8];
    #pragma unroll
    for (int j = 0; j < 8; ++j) acc[j] = 0.f;
    const float* ub = u + (size_t)b * DM * HW_;

    for (int c0 = 0; c0 < DM; c0 += 8) {
        __syncthreads();
        #pragma unroll
        for (int k = 0; k < 10; ++k) {
            const int i   = k * 256 + tid;
            const int cl  = i / 320;
            const int pos = i - cl * 320;
            const int rr  = pos >> 5;
            su[i] = ub[(c0 + cl) * HW_ + ((((h0 - 1 + rr) & 31) << 5) | (pos & 31))];
        }
        __syncthreads();
        #pragma unroll
        for (int cl = 0; cl < 8; ++cl) {
            #pragma unroll
            for (int kh = 0; kh < 3; ++kh) {
                const int rs = hl + kh;
                #pragma unroll
                for (int kw = 0; kw < 3; ++kw) {
                    const int ww = (w + kw + 31) & 31;
                    const float v = su[cl * 320 + ((rs << 5) | ww)];
                    const int wb = ((c0 + cl) * 9 + kh * 3 + kw) * 8;
                    const float4 w0 = *(const float4*)&sw[wb];
                    const float4 w1 = *(const float4*)&sw[wb + 4];
                    acc[0] = fmaf(v, w0.x, acc[0]);
                    acc[1] = fmaf(v, w0.y, acc[1]);
                    acc[2] = fmaf(v, w0.z, acc[2]);
                    acc[3] = fmaf(v, w0.w, acc[3]);
                    acc[4] = fmaf(v, w1.x, acc[4]);
                    acc[5] = fmaf(v, w1.y, acc[5]);
                    acc[6] = fmaf(v, w1.z, acc[6]);
                    acc[7] = fmaf(v, w1.w, acc[7]);
                }
            }
        }
    }

    if (mode == 0) {
        const float dt = dtp[0];
        #pragma unroll
        for (int j = 0; j < 8; ++j) {
            const float x  = acc[j] + bd[cbase + j] + dt;
            const float sp = fmaxf(x, 0.f) + log1pf(expf(-fabsf(x)));
            ws[WS_DELTA + ((size_t)b * DM + cbase + j) * HW_ + pix] = sp;
        }
    } else if (mode == 1) {
        #pragma unroll
        for (int j = 0; j < 8; ++j)
            ws[WS_BV + ((size_t)b * DS + cbase + j) * HW_ + pix] = acc[j];
    } else {
        #pragma unroll
        for (int j = 0; j < 8; ++j)
            ws[WS_CV + ((size_t)b * DS + cbase + j) * HW_ + pix] = acc[j];
    }
}

// ---------------------------------------------------------------------------
// Kernel 2 (v5): d_state split across threads. 512-thread blocks =
// 128 pixel-quads x 4 n-threads (nthr = tid>>7, wave-uniform -> coalescing
// preserved: each wave reads contiguous 1KB per n-plane). Each thread issues
// all 12 float4 loads up front (48 data VGPR, no pipeline staging), computes
// 4 n-slabs, NT-stores s_next. y reduced over the 4 n-threads via 8KB LDS.
// Block covers half a plane (512 px): grid = B*NV*DM*2 = 4608 blocks.
// ---------------------------------------------------------------------------
__global__ __launch_bounds__(512) void scan_kernel(
    const float* __restrict__ u,
    const float* __restrict__ s_prev,
    const float* __restrict__ logA,
    const float* __restrict__ Dv,
    const float* __restrict__ ws,
    float* __restrict__ out)
{
    const int bid  = blockIdx.x >> 1;   // (b*9+v)*64 + c
    const int half = blockIdx.x & 1;
    const int c   = bid & 63;
    const int bv  = bid >> 6;
    const int v   = bv % 9;
    const int b   = bv / 9;

    __shared__ float sAr[DS], sIr[DS];
    __shared__ float syl[4 * 512];      // [nthr][quad*4+j]

    const int tid = threadIdx.x;
    if (tid < DS) {
        const float A = -__expf(logA[(c << 4) + tid]);
        sAr[tid] = A;
        sIr[tid] = 1.0f / A;
    }
    __syncthreads();

    const int quad = tid & 127;
    const int nthr = tid >> 7;          // 0..3, wave-uniform
    const int lane = tid & 63;

    const int hw4 = (half << 9) | (quad << 2);   // first of 4 pixels
    const int h   = hw4 >> 5;

    const int sx  = v / 3 - 1;          // SHIFTS order: x outer, y inner
    const int syy = v % 3 - 1;
    const int hs  = (h + syy) & 31;
    const int rowbase = (hs << 5) | ((quad & 7) << 2);

    const int srcp = (lane & ~7) | ((lane + 1) & 7);  // next lane in row
    const int srcm = (lane & ~7) | ((lane + 7) & 7);  // prev lane in row

    const int bc = (b << 6) | c;
    const float4 u4 = *(const float4*)&u[(bc << 10) | hw4];
    const float4 d4 = *(const float4*)&ws[WS_DELTA + ((bc << 10) | hw4)];

    const float* __restrict__ sp  = s_prev + ((size_t)bid << 14);
    float* __restrict__ so        = out + Y_SIZE + ((size_t)bid << 14);
    const float* __restrict__ bvp = ws + WS_BV + ((b << 14) | hw4);
    const float* __restrict__ cvp = ws + WS_CV + ((b << 14) | hw4);

    // all 12 loads issued back-to-back
    float4 spv[4], bvv[4], cvv[4];
    #pragma unroll
    for (int i = 0; i < 4; ++i) {
        const int n = (nthr << 2) + i;
        spv[i] = *(const float4*)&sp[(n << 10) + rowbase];
        bvv[i] = *(const float4*)&bvp[n << 10];
        cvv[i] = *(const float4*)&cvp[n << 10];
    }

    float4 acc = make_float4(0.f, 0.f, 0.f, 0.f);
    #pragma unroll
    for (int i = 0; i < 4; ++i) {
        const int n = (nthr << 2) + i;
        float4 sh;
        if (sx > 0) {
            const float edge = __shfl(spv[i].x, srcp);
            sh = make_float4(spv[i].y, spv[i].z, spv[i].w, edge);
        } else if (sx < 0) {
            const float edge = __shfl(spv[i].w, srcm);
            sh = make_float4(edge, spv[i].x, spv[i].y, spv[i].z);
        } else {
            sh = spv[i];
        }
        const float A  = sAr[n];
        const float iA = sIr[n];
        float4 e;
        f32x4 s;
        e.x = __expf(d4.x * A);
        e.y = __expf(d4.y * A);
        e.z = __expf(d4.z * A);
        e.w = __expf(d4.w * A);
        s.x = fmaf(e.x, sh.x, (e.x - 1.f) * iA * bvv[i].x * u4.x);
        s.y = fmaf(e.y, sh.y, (e.y - 1.f) * iA * bvv[i].y * u4.y);
        s.z = fmaf(e.z, sh.z, (e.z - 1.f) * iA * bvv[i].z * u4.z);
        s.w = fmaf(e.w, sh.w, (e.w - 1.f) * iA * bvv[i].w * u4.w);
        __builtin_nontemporal_store(s, (f32x4*)&so[(n << 10) + hw4]);
        acc.x = fmaf(s.x, cvv[i].x, acc.x);
        acc.y = fmaf(s.y, cvv[i].y, acc.y);
        acc.z = fmaf(s.z, cvv[i].z, acc.z);
        acc.w = fmaf(s.w, cvv[i].w, acc.w);
    }

    // reduce y over the 4 n-threads
    *(float4*)&syl[(nthr << 9) | (quad << 2)] = make_float4(acc.x, acc.y, acc.z, acc.w);
    __syncthreads();
    if (tid < 128) {
        const float4 a0 = *(const float4*)&syl[(0 << 9) | (tid << 2)];
        const float4 a1 = *(const float4*)&syl[(1 << 9) | (tid << 2)];
        const float4 a2 = *(const float4*)&syl[(2 << 9) | (tid << 2)];
        const float4 a3 = *(const float4*)&syl[(3 << 9) | (tid << 2)];
        const float Dc = Dv[c];
        f32x4 y;
        y.x = a0.x + a1.x + a2.x + a3.x + u4.x * Dc;
        y.y = a0.y + a1.y + a2.y + a3.y + u4.y * Dc;
        y.z = a0.z + a1.z + a2.z + a3.z + u4.z * Dc;
        y.w = a0.w + a1.w + a2.w + a3.w + u4.w * Dc;
        __builtin_nontemporal_store(y, (f32x4*)&out[(bid << 10) | hw4]);
    }
}

extern "C" void kernel_launch(void* const* d_in, const int* in_sizes, int n_in,
                              void* d_out, int out_size, void* d_ws, size_t ws_size,
                              hipStream_t stream) {
    const float* u      = (const float*)d_in[0];
    const float* s_prev = (const float*)d_in[1];
    const float* Wd     = (const float*)d_in[2];
    const float* bd     = (const float*)d_in[3];
    const float* Wb     = (const float*)d_in[4];
    const float* Wc     = (const float*)d_in[5];
    const float* logA   = (const float*)d_in[6];
    const float* Dv     = (const float*)d_in[7];
    const float* dtp    = (const float*)d_in[8];
    float* out = (float*)d_out;
    float* ws  = (float*)d_ws;

    conv_kernel<<<B_ * 12 * 4, 256, 0, stream>>>(u, Wd, bd, Wb, Wc, dtp, ws);
    scan_kernel<<<B_ * NV * DM * 2, 512, 0, stream>>>(u, s_prev, logA, Dv, ws, out);
}